// Round 1
// baseline (540.424 us; speedup 1.0000x reference)
//
#include <hip/hip_runtime.h>

#define TOK 49
#define DIM 128
#define NHEAD 4
#define NWIN 1024

typedef __bf16 bf16x8 __attribute__((ext_vector_type(8)));
typedef float f32x4 __attribute__((ext_vector_type(4)));
typedef unsigned short u16;
typedef unsigned int u32;

// XOR swizzle: spreads stride-256B / stride-128B row accesses across banks.
__device__ __forceinline__ int xo256(int row, int kbyte) {
    return row * 256 + (kbyte ^ ((row & 7) << 4));
}
__device__ __forceinline__ int xo128(int row, int kbyte) {
    return row * 128 + (kbyte ^ ((row & 7) << 4));
}
__device__ __forceinline__ bf16x8 cvt8(const float* __restrict__ p) {
    float4 a = *reinterpret_cast<const float4*>(p);
    float4 bq = *reinterpret_cast<const float4*>(p + 4);
    bf16x8 r;
    r[0] = (__bf16)a.x; r[1] = (__bf16)a.y; r[2] = (__bf16)a.z; r[3] = (__bf16)a.w;
    r[4] = (__bf16)bq.x; r[5] = (__bf16)bq.y; r[6] = (__bf16)bq.z; r[7] = (__bf16)bq.w;
    return r;
}
__device__ __forceinline__ u16 bfbits(float x) {
    __bf16 t = (__bf16)x;
    return __builtin_bit_cast(u16, t);
}

__global__ __launch_bounds__(256, 2) void winattn_kernel(
    const float* __restrict__ q, const float* __restrict__ k, const float* __restrict__ v,
    const float* __restrict__ mask, const float* __restrict__ Wq, const float* __restrict__ Wk,
    const float* __restrict__ Wv, const float* __restrict__ Wo, const float* __restrict__ bo,
    const float* __restrict__ rel, float* __restrict__ out)
{
    __shared__ __align__(16) char lds[65536];
    char* xs = lds;          // [64][128] bf16 swizzled: staging x, later outh
    char* qh = lds + 16384;  // [64][128] bf16 swizzled
    char* kh = lds + 32768;  // [64][128] bf16 swizzled
    char* vt = lds + 49152;  // [128][64] bf16 swizzled (v projection, transposed)
    // attn buffers (per wave, [64][64] bf16 swizzled) alias qh/kh after QK^T.

    const int tid = threadIdx.x;
    const int wave = tid >> 6;
    const int lane = tid & 63;
    const int l16 = lane & 15;
    const int k8 = lane >> 4;
    const int b = blockIdx.x;

    const float* qp = q + (size_t)b * (TOK * DIM);
    const float* kp = k + (size_t)b * (TOK * DIM);
    const float* vp = v + (size_t)b * (TOK * DIM);
    const float* mp = mask + (size_t)(b & (NWIN - 1)) * (TOK * TOK);
    float* op = out + (size_t)b * (TOK * DIM);

    // ---- stage [49][128] fp32 -> xs bf16, zero-pad rows 49..63 ----
    auto stage = [&](const float* __restrict__ src) {
        const int c = tid & 15;   // 8-float chunk within row
        const int r0 = tid >> 4;  // 16 rows per pass
        #pragma unroll
        for (int pp = 0; pp < 4; ++pp) {
            const int row = pp * 16 + r0;
            bf16x8 v8;
            if (row < TOK) {
                v8 = cvt8(src + row * DIM + c * 8);
            } else {
                #pragma unroll
                for (int j = 0; j < 8; ++j) v8[j] = (__bf16)0.0f;
            }
            *reinterpret_cast<bf16x8*>(xs + xo256(row, c * 16)) = v8;
        }
    };

    // ---- weight B-fragments: wave owns output cols [wave*32, wave*32+32) ----
    bf16x8 bw[2][4];
    auto load_w = [&](const float* __restrict__ W) {
        #pragma unroll
        for (int n = 0; n < 2; ++n) {
            const int o = (wave * 2 + n) * 16 + l16;
            #pragma unroll
            for (int kk = 0; kk < 4; ++kk)
                bw[n][kk] = cvt8(W + o * DIM + kk * 32 + k8 * 8);
        }
    };

    f32x4 acc[4][2];
    auto proj = [&]() {
        #pragma unroll
        for (int mi = 0; mi < 4; ++mi) {
            const int row = mi * 16 + l16;
            bf16x8 a[4];
            #pragma unroll
            for (int kk = 0; kk < 4; ++kk)
                a[kk] = *reinterpret_cast<const bf16x8*>(xs + xo256(row, kk * 64 + k8 * 16));
            #pragma unroll
            for (int n = 0; n < 2; ++n) {
                f32x4 c = {0.f, 0.f, 0.f, 0.f};
                #pragma unroll
                for (int kk = 0; kk < 4; ++kk)
                    c = __builtin_amdgcn_mfma_f32_16x16x32_bf16(a[kk], bw[n][kk], c, 0, 0, 0);
                acc[mi][n] = c;
            }
        }
    };

    // C-frag (16x16x32): row = k8*4+r (+16*mi), col = l16 (+16*n-tile)  [m89]
    auto write_rm = [&](char* dst) {
        #pragma unroll
        for (int mi = 0; mi < 4; ++mi) {
            #pragma unroll
            for (int n = 0; n < 2; ++n) {
                const int col = (wave * 2 + n) * 16 + l16;
                #pragma unroll
                for (int r = 0; r < 4; ++r) {
                    const int row = mi * 16 + k8 * 4 + r;
                    *reinterpret_cast<u16*>(dst + xo256(row, col * 2)) = bfbits(acc[mi][n][r]);
                }
            }
        }
    };

    auto write_vt = [&]() {  // transposed: vt[dim][m], 4 consecutive m pack to b64
        #pragma unroll
        for (int mi = 0; mi < 4; ++mi) {
            #pragma unroll
            for (int n = 0; n < 2; ++n) {
                const int dim = (wave * 2 + n) * 16 + l16;
                const int m0 = mi * 16 + k8 * 4;
                uint2 pk;
                pk.x = (u32)bfbits(acc[mi][n][0]) | ((u32)bfbits(acc[mi][n][1]) << 16);
                pk.y = (u32)bfbits(acc[mi][n][2]) | ((u32)bfbits(acc[mi][n][3]) << 16);
                *reinterpret_cast<uint2*>(vt + xo128(dim, m0 * 2)) = pk;
            }
        }
    };

    // ================= pipeline =================
    stage(qp);
    __syncthreads();
    load_w(Wq); proj(); write_rm(qh);
    __syncthreads();
    stage(kp);
    __syncthreads();
    load_w(Wk); proj(); write_rm(kh);
    __syncthreads();
    stage(vp);
    __syncthreads();
    load_w(Wv); proj(); write_vt();
    __syncthreads();

    // ---- QK^T, swapped: E^T[m][l] = sum_d kh[m][d]*qh[l][d]; head = wave ----
    const int h = wave;
    f32x4 e[4][4];  // [mi: m-tile][ni: l-tile]
    {
        bf16x8 ak[4], bq[4];
        #pragma unroll
        for (int mi = 0; mi < 4; ++mi)
            ak[mi] = *reinterpret_cast<const bf16x8*>(kh + xo256(mi * 16 + l16, h * 64 + k8 * 16));
        #pragma unroll
        for (int ni = 0; ni < 4; ++ni)
            bq[ni] = *reinterpret_cast<const bf16x8*>(qh + xo256(ni * 16 + l16, h * 64 + k8 * 16));
        #pragma unroll
        for (int mi = 0; mi < 4; ++mi) {
            #pragma unroll
            for (int ni = 0; ni < 4; ++ni) {
                f32x4 c = {0.f, 0.f, 0.f, 0.f};
                e[mi][ni] = __builtin_amdgcn_mfma_f32_16x16x32_bf16(ak[mi], bq[ni], c, 0, 0, 0);
            }
        }
    }
    __syncthreads();  // all waves done reading qh/kh; attn may now alias them

    char* at = lds + 16384 + wave * 8192;  // [64][64] bf16 swizzled, this wave's attn
    {
        const float scale = 0.17677669529663687f;  // 1/sqrt(32)
        // scale + rel-pos bias + shift mask; -1e30 on padded rows/cols
        #pragma unroll
        for (int ni = 0; ni < 4; ++ni) {
            const int l = ni * 16 + l16;
            const int lh7 = l / 7, lw7 = l % 7;
            #pragma unroll
            for (int mi = 0; mi < 4; ++mi) {
                #pragma unroll
                for (int r = 0; r < 4; ++r) {
                    const int m = mi * 16 + k8 * 4 + r;
                    float val = -1e30f;
                    if (l < TOK && m < TOK) {
                        const int dl = lh7 - m / 7 + 6;
                        const int dc = lw7 - m % 7 + 6;
                        val = e[mi][ni][r] * scale + rel[(dl * 13 + dc) * NHEAD + h]
                              + mp[l * TOK + m];
                    }
                    e[mi][ni][r] = val;
                }
            }
        }
        // softmax over m: 16 in-lane values + shfl_xor across k8 groups
        #pragma unroll
        for (int ni = 0; ni < 4; ++ni) {
            float mx = -1e30f;
            #pragma unroll
            for (int mi = 0; mi < 4; ++mi) {
                #pragma unroll
                for (int r = 0; r < 4; ++r) mx = fmaxf(mx, e[mi][ni][r]);
            }
            mx = fmaxf(mx, __shfl_xor(mx, 16));
            mx = fmaxf(mx, __shfl_xor(mx, 32));
            float s = 0.f;
            #pragma unroll
            for (int mi = 0; mi < 4; ++mi) {
                #pragma unroll
                for (int r = 0; r < 4; ++r) {
                    const float p = __expf(e[mi][ni][r] - mx);
                    e[mi][ni][r] = p;
                    s += p;
                }
            }
            s += __shfl_xor(s, 16);
            s += __shfl_xor(s, 32);
            const float rs = 1.0f / s;
            // store attn row l: 4 consecutive m per b64 write
            #pragma unroll
            for (int mi = 0; mi < 4; ++mi) {
                const int m0 = mi * 16 + k8 * 4;
                uint2 pk;
                pk.x = (u32)bfbits(e[mi][ni][0] * rs) | ((u32)bfbits(e[mi][ni][1] * rs) << 16);
                pk.y = (u32)bfbits(e[mi][ni][2] * rs) | ((u32)bfbits(e[mi][ni][3] * rs) << 16);
                *reinterpret_cast<uint2*>(at + xo128(ni * 16 + l16, m0 * 2)) = pk;
            }
        }
    }

    // ---- PV: outh[l][h*32+d] = sum_m attn[l][m] * vt[h*32+d][m] ----
    f32x4 oacc[4][2];
    {
        bf16x8 bv[2][2];
        #pragma unroll
        for (int n = 0; n < 2; ++n) {
            const int dim = h * 32 + n * 16 + l16;
            #pragma unroll
            for (int kk = 0; kk < 2; ++kk)
                bv[n][kk] = *reinterpret_cast<const bf16x8*>(vt + xo128(dim, kk * 64 + k8 * 16));
        }
        #pragma unroll
        for (int mi = 0; mi < 4; ++mi) {
            const int row = mi * 16 + l16;
            bf16x8 pa[2];
            #pragma unroll
            for (int kk = 0; kk < 2; ++kk)
                pa[kk] = *reinterpret_cast<const bf16x8*>(at + xo128(row, kk * 64 + k8 * 16));
            #pragma unroll
            for (int n = 0; n < 2; ++n) {
                f32x4 c = {0.f, 0.f, 0.f, 0.f};
                c = __builtin_amdgcn_mfma_f32_16x16x32_bf16(pa[0], bv[n][0], c, 0, 0, 0);
                c = __builtin_amdgcn_mfma_f32_16x16x32_bf16(pa[1], bv[n][1], c, 0, 0, 0);
                oacc[mi][n] = c;
            }
        }
    }
    // outh -> xs (row-major bf16, swizzled); xs free since v-projection barrier
    #pragma unroll
    for (int mi = 0; mi < 4; ++mi) {
        #pragma unroll
        for (int n = 0; n < 2; ++n) {
            const int col = h * 32 + n * 16 + l16;
            #pragma unroll
            for (int r = 0; r < 4; ++r) {
                const int row = mi * 16 + k8 * 4 + r;
                *reinterpret_cast<u16*>(xs + xo256(row, col * 2)) = bfbits(oacc[mi][n][r]);
            }
        }
    }
    __syncthreads();

    // ---- output projection, swapped: out^T[o][l] = sum_i Wo[o][i]*outh[l][i] ----
    // C-frag regs = 4 consecutive o -> packed float4 global store with fused bias.
    {
        bf16x8 aw[2][4];
        #pragma unroll
        for (int m2 = 0; m2 < 2; ++m2) {
            const int o = (wave * 2 + m2) * 16 + l16;
            #pragma unroll
            for (int kk = 0; kk < 4; ++kk)
                aw[m2][kk] = cvt8(Wo + o * DIM + kk * 32 + k8 * 8);
        }
        #pragma unroll
        for (int ni = 0; ni < 4; ++ni) {
            const int l = ni * 16 + l16;
            bf16x8 bx[4];
            #pragma unroll
            for (int kk = 0; kk < 4; ++kk)
                bx[kk] = *reinterpret_cast<const bf16x8*>(xs + xo256(l, kk * 64 + k8 * 16));
            #pragma unroll
            for (int m2 = 0; m2 < 2; ++m2) {
                f32x4 c = {0.f, 0.f, 0.f, 0.f};
                #pragma unroll
                for (int kk = 0; kk < 4; ++kk)
                    c = __builtin_amdgcn_mfma_f32_16x16x32_bf16(aw[m2][kk], bx[kk], c, 0, 0, 0);
                if (l < TOK) {
                    const int o0 = (wave * 2 + m2) * 16 + k8 * 4;
                    const float4 bias = *reinterpret_cast<const float4*>(bo + o0);
                    float4 st;
                    st.x = c[0] + bias.x;
                    st.y = c[1] + bias.y;
                    st.z = c[2] + bias.z;
                    st.w = c[3] + bias.w;
                    *reinterpret_cast<float4*>(op + l * DIM + o0) = st;
                }
            }
        }
    }
}

extern "C" void kernel_launch(void* const* d_in, const int* in_sizes, int n_in,
                              void* d_out, int out_size, void* d_ws, size_t ws_size,
                              hipStream_t stream) {
    const float* q    = (const float*)d_in[0];
    const float* k    = (const float*)d_in[1];
    const float* v    = (const float*)d_in[2];
    const float* mask = (const float*)d_in[3];
    const float* Wq   = (const float*)d_in[4];
    const float* Wk   = (const float*)d_in[5];
    const float* Wv   = (const float*)d_in[6];
    const float* Wo   = (const float*)d_in[7];
    const float* bo   = (const float*)d_in[8];
    const float* rel  = (const float*)d_in[9];
    float* out = (float*)d_out;

    const int B = in_sizes[0] / (TOK * DIM);  // 8192 windows
    winattn_kernel<<<dim3(B), dim3(256), 0, stream>>>(q, k, v, mask, Wq, Wk, Wv, Wo, bo,
                                                      rel, out);
}